// Round 5
// baseline (249.068 us; speedup 1.0000x reference)
//
#include <hip/hip_runtime.h>
#include <stdint.h>

// SNN forward with STP/STDP, delays {1,2,3,5}, B=8 T=64 NI=256 N=512 NO=32 D=4.
// Persistent dataflow kernel: 256 blocks = 8 batches x 32 o-chunks (16 o's).
// ROUND-5: occupancy push #2 + barrier halving.
//  * 1024 threads/block = 16 waves/CU = 4 waves/SIMD (r4 proved waves/SIMD is
//    THE lever: 1->2 waves/SIMD gave -27%). 64 e-groups x 8 synapses/lane.
//  * ONE raw barrier per step (was 2): sxq and red are double-buffered by t&1;
//    step = {prefetch, acc(sxq[cur]), red[cur]-write, stage(sxq[nxt]), BAR,
//    syn(red[cur]), update, publish, STDP}. Barrier transitivity orders the
//    t/t+2 buffer reuse; cross-block cadence (publish step-t tail -> peer
//    staging step t+1) unchanged; parity poll backstops skew.
//  * prefetch/staging split: each thread owns 2 of the 4 delay planes
//    (hi = tid>>9). Delay-1 plane agent-loaded + staged last; delay>=2 planes
//    plain-loaded (L1/L2-cacheable; write-once data => stale == wrong parity
//    -> agent poll fallback).
// Cross-block recurrence: ONE packed 8B record per (t,b,n) = {syn_p, xbar|spike},
// agent-scope relaxed store; "unwritten" = RUN-PARITY TAG in syn_p's sign bit
// (syn_p >= 0 always). Workspace re-poisoned every run (measured) => init
// always runs: parity-fill own rec slice + one done[]-tag grid barrier.
// Readout fused: per-step 16-bit spike ballot -> partial h2 -> f32 atomics ->
// batch-last block scans. Single dispatch, no memsets.

#define B  8
#define T  64
#define NI 256
#define NN 512
#define NO 32
#define DD 4

#define NBLK 256
#define TPB  1024
#define OPB  16          // o's per block
#define EGR  64          // e-groups (tid>>4)
#define SPL  8           // synapses per lane (e = e_grp + 64*i)
#define EPAD 516         // padded per-d LDS plane stride (float2 elems)

#define REC_ELEMS (T*B*NN)   // packed 8B records
#define MAGIC  0x534E4E31u

// ctrl[] layout (u32): [0..7]=cnt per batch, [8]=gcnt, [9]=runpar, [10]=header,
//                      [16..271]=done[] per-block init tags
#define C_CNT   0
#define C_GCNT  8
#define C_PAR   9
#define C_HDR   10
#define C_DONE  16

__device__ __forceinline__ unsigned long long rec_load(const unsigned long long* p) {
    return __hip_atomic_load(p, __ATOMIC_RELAXED, __HIP_MEMORY_SCOPE_AGENT);
}
__device__ __forceinline__ unsigned long long rec_load_plain(const unsigned long long* p) {
    return *p;   // L1/L2-cacheable; write-once data => stale == wrong parity
}
__device__ __forceinline__ void rec_store(unsigned long long* p, unsigned long long v) {
    __hip_atomic_store(p, v, __ATOMIC_RELAXED, __HIP_MEMORY_SCOPE_AGENT);
}
__device__ __forceinline__ unsigned ctrl_ld(const unsigned* p) {
    return __hip_atomic_load(p, __ATOMIC_RELAXED, __HIP_MEMORY_SCOPE_AGENT);
}
__device__ __forceinline__ void ctrl_st(unsigned* p, unsigned v) {
    __hip_atomic_store(p, v, __ATOMIC_RELAXED, __HIP_MEMORY_SCOPE_AGENT);
}
__device__ __forceinline__ bool unwritten(unsigned long long v, unsigned runpar) {
    return ((unsigned)v >> 31) != runpar;   // lo sign bit = run parity tag
}
__device__ __forceinline__ unsigned long long poll_written(
        const unsigned long long* src, unsigned long long v, unsigned runpar) {
    int guard = 0;
    while (unwritten(v, runpar)) {
        if (guard >= 2) __builtin_amdgcn_s_sleep(1);   // fast-retry first
        v = rec_load(src);                             // authoritative (agent)
        if (++guard > (1 << 18)) break;                // fail loud, not hung
    }
    return v;
}

// Raw barrier: drain LDS only (NOT vmcnt) -- prefetch loads / publish store
// stay in flight across the barrier. Compiler still inserts counted vmcnt
// waits before any use of load results.
#define BAR_LDS() do {                                      \
    asm volatile("s_waitcnt lgkmcnt(0)" ::: "memory");      \
    __builtin_amdgcn_s_barrier();                           \
    asm volatile("" ::: "memory");                          \
} while (0)

__global__ __launch_bounds__(TPB, 4)
void snn_main(const float* __restrict__ inputs,
              const float* __restrict__ w,
              const float* __restrict__ w_in,
              const float* __restrict__ w_out,
              const float* __restrict__ dmap,
              const int*   __restrict__ delays,
              const float* __restrict__ w_signs,
              const float* __restrict__ p,
              const float* __restrict__ A_p,
              const float* __restrict__ A_d,
              unsigned long long* __restrict__ rec,
              float* __restrict__ h2buf,
              unsigned* __restrict__ ctrl,
              float* __restrict__ out)
{
    // LDS: double-buffered sxq planes {syn_p, xbar|spikebit}: 2 x 16512 B.
    __shared__ float2 sxq[2][DD*EPAD];
    __shared__ float  inp_s[T*OPB];        // per-block input-current slice
    __shared__ float  red[2][16*OPB];      // 16 wave partials, double-buffered
    __shared__ unsigned int spikebits_s[T];// this block's 16 neurons' spikes per step
    __shared__ float  wout16_s[OPB*NO];    // w_out rows of this block's neurons
    __shared__ float  h2_s[T*NO];          // last-block scan staging
    __shared__ int    last_s;

    const int tid     = threadIdx.x;
    const int bid     = blockIdx.x;
    const int b       = bid & 7;           // round-robin => batch b lives on XCD b
    const int chunk   = bid >> 3;
    const int o_base  = chunk * OPB;
    const int o_local = tid & 15;
    const int e_grp   = tid >> 4;          // 0..63
    const int o       = o_base + o_local;
    const int slotid  = tid & 511;         // rec slot this thread stages
    const int hi      = tid >> 9;          // plane-pair selector (wave-uniform)

    // ---------------- init (runs every launch: ws is re-poisoned) -----------
    unsigned runpar;
    if (ctrl_ld(ctrl + C_HDR) != MAGIC) {
        // fill own rec slice: lo-sign=1 => "unwritten for run parity 0"
        rec_store(rec + (size_t)bid * (REC_ELEMS / NBLK) + tid,
                  0x0000000080000000ull);
        // zero own h2 slice
        if (tid < (B*T*NO) / NBLK)
            ctrl_st((unsigned*)h2buf + (size_t)bid * ((B*T*NO) / NBLK) + tid, 0u);
        if (bid == 0 && tid < 10) ctrl_st(ctrl + tid, 0u);  // cnt[8], gcnt, par
        __syncthreads();                    // drains vmcnt(0): all stores acked
        if (tid == 0) ctrl_st(ctrl + C_DONE + bid, MAGIC);
        // single grid arrival barrier: thread j (<256) watches done[j]
        if (tid < NBLK) {
            int guard = 0;
            while (ctrl_ld(ctrl + C_DONE + tid) != MAGIC) {
                __builtin_amdgcn_s_sleep(2);
                if (++guard > (1 << 20)) break;
            }
        }
        __syncthreads();
        runpar = 0u;
    } else {
        runpar = ctrl_ld(ctrl + C_PAR);     // ws persisted: fast path
    }

    // ---- publish slot 0 (zero record, parity-tagged) FIRST ----
    if (tid < OPB) {
        rec_store(rec + (size_t)(0*B + b)*NN + o_base + tid,
                  (unsigned long long)(runpar << 31));
    }
    if (tid == 0) spikebits_s[0] = 0u;

    // ---------------- per-lane synapse constants (registers) -----------------
    float wv[SPL], ap[SPL], ad[SPL], ws[SPL];
    int   laddr[SPL];                 // LDS byte offset of (d,e) slot in buffer 0
    #pragma unroll
    for (int i = 0; i < SPL; ++i) {
        const int e = e_grp + EGR*i;
        wv[i] = w_signs[e] * fabsf(w[e*NN + o]);
        ap[i] = A_p[e*NN + o];
        ad[i] = A_d[e*NN + o];
        int d = 0;                    // argmax_d of one-hot dmap
        if (dmap[1*NN*NN + e*NN + o] != 0.0f) d = 1;
        if (dmap[2*NN*NN + e*NN + o] != 0.0f) d = 2;
        if (dmap[3*NN*NN + e*NN + o] != 0.0f) d = 3;
        ws[i]    = 1.0f;
        laddr[i] = (d*EPAD + e) * 8;
    }
    int del[DD];
    #pragma unroll
    for (int d = 0; d < DD; ++d) del[d] = delays[d];
    // plane ownership: hi=0 -> {1,3}, hi=1 -> {2,0}; delay-1 plane (d=0) last
    const int dj0 = hi ? 2 : 1;
    const int dj1 = hi ? 0 : 3;

    // ---------------- prologue: inp[b,t,o] slice = inputs @ w_in -------------
    {
        float* win = (float*)sxq;     // 4096 floats alias buffer 0, prologue-only
        #pragma unroll
        for (int q = 0; q < NI*OPB/TPB; ++q) {
            const int k = q*TPB + tid;
            const int c = k >> 4, oo = k & 15;
            win[c*OPB + oo] = w_in[c*NN + o_base + oo];
        }
        __syncthreads();
        {   // one (t,o) entry per thread: 256-MAC row
            const int tj = tid >> 4;
            const float* inrow = inputs + (size_t)(b*T + tj)*NI;
            float a = 0.f;
            for (int c = 0; c < NI; ++c) a += inrow[c] * win[c*OPB + o_local];
            __syncthreads();          // all win reads done before overwrite below
            inp_s[tj*OPB + o_local] = a;
        }
    }

    // zero-fill sxq buffer 0 for step 0 (delays > 0 => all gathered slots zero);
    // buffer 1 is fully staged during step 0.
    if (tid < 512) {
        #pragma unroll
        for (int d = 0; d < DD; ++d)
            sxq[0][d*EPAD + tid] = make_float2(0.f, 0.f);
    }
    __syncthreads();

    // neuron state, replicated across the 64 e_grp threads sharing an o
    float mem = 0.f, w_p = 0.f, x_bar = 0.f, u_pot = 0.f, u_dep = 0.f;
    const float p_o  = p[o];
    const float pd_o = (p_o < 0.f) ? 1.f : 0.f;

    for (int t = 0; t < T; ++t) {
        const int cur = t & 1, nxt = cur ^ 1;
        const char* sxc = (const char*)&sxq[cur][0];

        // ---- prefetch this thread's 2 delay planes for step t+1 ----
        unsigned long long pf0 = 0ull, pf1 = 0ull;
        if (t + 1 < T) {
            if (t + 1 >= del[dj0]) {
                const int s = (t + 1 - del[dj0]) & 63;
                const unsigned long long* src = rec + (size_t)(s*B + b)*NN + slotid;
                pf0 = (del[dj0] == 1) ? rec_load(src) : rec_load_plain(src);
            }
            if (t + 1 >= del[dj1]) {
                const int s = (t + 1 - del[dj1]) & 63;
                const unsigned long long* src = rec + (size_t)(s*B + b)*NN + slotid;
                pf1 = (del[dj1] == 1) ? rec_load(src) : rec_load_plain(src);
            }
        }

        // ---- acc-only loop: 8 synapses/lane, staged v[] kept in registers ----
        const float spike = (mem > 1.0f) ? 1.0f : 0.0f;
        const float pg  = spike * fmaxf(u_pot, 0.f);   // STDP gates: pre-update u's
        const float udr = fmaxf(u_dep, 0.f);
        float2 v[SPL];
        float acc = 0.f;
        #pragma unroll
        for (int i = 0; i < SPL; ++i) {
            v[i] = *(const float2*)(sxc + laddr[i]);
            acc = fmaf(v[i].x, wv[i]*ws[i], acc);      // syn uses OLD w_stdp
        }
        // reduce over e: intra-wave xor-shuffles (4 e_grps/wave), 16 wave partials
        float a2 = acc + __shfl_xor(acc, 16);
        a2 += __shfl_xor(a2, 32);
        if ((tid & 63) < 16) red[cur][(tid >> 6)*16 + o_local] = a2;

        // ---- stage step t+1 into sxq[nxt] (before the single barrier) ----
        if (t + 1 < T) {
            {
                unsigned long long v0 = (unsigned long long)(runpar << 31);
                if (t + 1 >= del[dj0]) {
                    const int s = (t + 1 - del[dj0]) & 63;
                    v0 = poll_written(rec + (size_t)(s*B + b)*NN + slotid, pf0, runpar);
                }
                sxq[nxt][dj0*EPAD + slotid] =
                    make_float2(__uint_as_float((unsigned)v0 & 0x7fffffffu),
                                __uint_as_float((unsigned)(v0 >> 32)));
            }
            {
                unsigned long long v1 = (unsigned long long)(runpar << 31);
                if (t + 1 >= del[dj1]) {
                    const int s = (t + 1 - del[dj1]) & 63;
                    v1 = poll_written(rec + (size_t)(s*B + b)*NN + slotid, pf1, runpar);
                }
                sxq[nxt][dj1*EPAD + slotid] =
                    make_float2(__uint_as_float((unsigned)v1 & 0x7fffffffu),
                                __uint_as_float((unsigned)(v1 >> 32)));
            }
        }

        BAR_LDS();   // THE step barrier: red[cur] + sxq[nxt] visible block-wide

        float syn = 0.f;
        #pragma unroll
        for (int k = 0; k < 16; ++k) syn += red[cur][k*16 + o_local];

        // ---- state updates (reference order; u's use pre-update mem) ----
        const float wp_new = 0.85f*w_p + spike * p_o * (1.f + pd_o*w_p);
        const float xb_new = 0.95f*x_bar + 0.05f*spike;
        u_pot = 0.95f*u_pot + 0.05f*mem;
        u_dep = 0.95f*u_dep + 0.05f*mem;
        mem   = 0.9f*mem + inp_s[t*OPB + o_local] + syn - spike;
        w_p   = wp_new;
        x_bar = xb_new;

        // ---- publish record for step t+1 (pre-update values of t+1) ----
        if (t + 1 < T && tid < OPB) {
            const float spike1 = (mem > 1.0f) ? 1.0f : 0.0f;
            const float sp = spike1 * (1.f + w_p);     // >= 0: sign bit free
            const unsigned int xu = __float_as_uint(x_bar) | (spike1 != 0.f ? 0x80000000u : 0u);
            const unsigned int lo = __float_as_uint(sp) | (runpar << 31);
            const unsigned long long pk = ((unsigned long long)xu << 32) | lo;
            rec_store(rec + (size_t)((t+1)*B + b)*NN + o_base + tid, pk);
            const unsigned long long bal = __ballot(spike1 != 0.0f);
            if (tid == 0) spikebits_s[t+1] = (unsigned int)bal;
        }

        // ---- STDP ws-update (covers publish visibility; pre-update gates) ----
        #pragma unroll
        for (int i = 0; i < SPL; ++i) {
            const unsigned int xu = __float_as_uint(v[i].y);
            const float dep = ((int)xu < 0) ? ad[i]*udr : 0.f;  // X in sign bit
            const float pot = (ap[i]*pg) * fabsf(v[i].y);
            ws[i] = fminf(fmaxf(ws[i] + pot - dep, 0.f), 2.f);
        }
        // no trailing barrier: next step's readers use the other buffers;
        // t/t+2 buffer reuse is ordered by barrier transitivity.
    }

    // ================= fused readout =================
    __syncthreads();   // all step-63 red/sxq traffic fully done
    // (1) per-block partial h2 over its own 16 neurons, from the LDS spike bitmap
    if (tid < OPB*NO) wout16_s[tid] = w_out[(o_base + (tid >> 5))*NO + (tid & 31)];
    __syncthreads();

    const int g  = tid >> 5;        // 0..31
    const int oo = tid & 31;        // output index
    #pragma unroll
    for (int j = 0; j < 2; ++j) {
        const int t = g*2 + j;
        const unsigned int bits = spikebits_s[t];
        float a = 0.f;
        #pragma unroll
        for (int i = 0; i < OPB; ++i)
            if (bits & (1u << i)) a += wout16_s[i*NO + oo];
        if (a != 0.f) atomicAdd(h2buf + ((size_t)b*T + t)*NO + oo, a);
    }
    __threadfence();                 // make our h2 atomics visible before arrival
    __syncthreads();
    if (tid == 0) last_s = (atomicAdd(ctrl + C_CNT + b, 1u) == 31u) ? 1 : 0;
    __syncthreads();

    if (last_s) {
        // (2) last-arriving block of batch b: gather h2, leaky scan, reset h2
        __threadfence();
        #pragma unroll
        for (int j = 0; j < 2; ++j) {
            const int t = g*2 + j;
            h2_s[t*NO + oo] = __hip_atomic_load(h2buf + ((size_t)b*T + t)*NO + oo,
                                                __ATOMIC_RELAXED, __HIP_MEMORY_SCOPE_AGENT);
        }
        __syncthreads();
        #pragma unroll
        for (int j = 0; j < 2; ++j) {   // zero-after-read (persisted-ws path safety)
            const int t = g*2 + j;
            __hip_atomic_store((unsigned*)(h2buf + ((size_t)b*T + t)*NO + oo), 0u,
                               __ATOMIC_RELAXED, __HIP_MEMORY_SCOPE_AGENT);
        }
        if (tid < NO) {
            float st = 0.f;
            for (int t = 0; t < T; ++t) {
                st = 0.9f*st + h2_s[t*NO + tid];
                out[((size_t)b*T + t)*NO + tid] = st;
            }
        }
    }

    // ---- global arrival: the 256th block flips run state for the next launch ----
    if (tid == 0) {
        const unsigned gar = __hip_atomic_fetch_add(ctrl + C_GCNT, 1u,
                                                    __ATOMIC_ACQ_REL, __HIP_MEMORY_SCOPE_AGENT);
        if (gar == NBLK - 1) {
            for (int i = 0; i < 8; ++i) ctrl_st(ctrl + C_CNT + i, 0u);
            ctrl_st(ctrl + C_GCNT, 0u);
            ctrl_st(ctrl + C_PAR, runpar ^ 1u);
            ctrl_st(ctrl + C_HDR, MAGIC);
        }
    }
}

extern "C" void kernel_launch(void* const* d_in, const int* in_sizes, int n_in,
                              void* d_out, int out_size, void* d_ws, size_t ws_size,
                              hipStream_t stream)
{
    const float* inputs  = (const float*)d_in[0];
    const float* w       = (const float*)d_in[1];
    const float* w_in    = (const float*)d_in[2];
    const float* w_out   = (const float*)d_in[3];
    const float* dmap    = (const float*)d_in[4];
    const int*   delays  = (const int*)  d_in[5];
    const float* w_signs = (const float*)d_in[6];
    const float* p       = (const float*)d_in[7];
    const float* A_p     = (const float*)d_in[8];
    const float* A_d     = (const float*)d_in[9];

    char* wsb = (char*)d_ws;
    unsigned long long* rec = (unsigned long long*)wsb;            // 2 MB packed records
    float* h2buf = (float*)(wsb + (size_t)REC_ELEMS*8);            // 64 KB
    unsigned* ctrl = (unsigned*)(wsb + (size_t)REC_ELEMS*8 + (size_t)B*T*NO*4);

    // Single dispatch: init (parity fill + one grid tag-barrier) runs in-kernel.
    hipLaunchKernelGGL(snn_main, dim3(NBLK), dim3(TPB), 0, stream,
                       inputs, w, w_in, w_out, dmap, delays, w_signs, p, A_p, A_d,
                       rec, h2buf, ctrl, (float*)d_out);
}

// Round 6
// 238.121 us; speedup vs baseline: 1.0460x; 1.0460x over previous
//
#include <hip/hip_runtime.h>
#include <stdint.h>

// SNN forward with STP/STDP, delays {1,2,3,5}, B=8 T=64 NI=256 N=512 NO=32 D=4.
// Persistent dataflow kernel: 256 blocks = 8 batches x 32 o-chunks (16 o's).
// ROUND-6: r4's verified step ORDERING (publish decoupled from staging polls,
// two lgkmcnt-only barriers, long prefetch->consume gap) + r5's occupancy
// (1024 threads = 16 waves = 4 waves/SIMD; 64 e-groups x 8 synapses/lane;
// each thread owns 2 of the 4 delay planes, hi = tid>>9).
// Step = {prefetch(2 planes), acc(sxq), red-write, BAR1, syn, update,
//         PUBLISH, STDP, staging+polls, BAR2}.
// Cross-block recurrence: ONE packed 8B record per (t,b,n) = {syn_p, xbar|spike},
// agent-scope relaxed store; "unwritten" = RUN-PARITY TAG in syn_p's sign bit
// (syn_p >= 0 always since w_p > -1). Delay-1 plane agent-loaded (first touch);
// delay>=2 planes plain-loaded (L1/L2-cacheable; write-once => stale == wrong
// parity -> agent poll fallback). Workspace re-poisoned every run (measured)
// => init always runs: parity-fill own rec slice + one done[]-tag grid barrier.
// Readout fused: per-step 16-bit spike ballot -> partial h2 -> f32 atomics ->
// batch-last block scans. Single dispatch, no memsets.

#define B  8
#define T  64
#define NI 256
#define NN 512
#define NO 32
#define DD 4

#define NBLK 256
#define TPB  1024
#define OPB  16          // o's per block
#define EGR  64          // e-groups (tid>>4)
#define SPL  8           // synapses per lane (e = e_grp + 64*i)
#define EPAD 516         // padded per-d LDS plane stride (float2 elems)

#define REC_ELEMS (T*B*NN)   // packed 8B records
#define MAGIC  0x534E4E31u

// ctrl[] layout (u32): [0..7]=cnt per batch, [8]=gcnt, [9]=runpar, [10]=header,
//                      [16..271]=done[] per-block init tags
#define C_CNT   0
#define C_GCNT  8
#define C_PAR   9
#define C_HDR   10
#define C_DONE  16

__device__ __forceinline__ unsigned long long rec_load(const unsigned long long* p) {
    return __hip_atomic_load(p, __ATOMIC_RELAXED, __HIP_MEMORY_SCOPE_AGENT);
}
__device__ __forceinline__ unsigned long long rec_load_plain(const unsigned long long* p) {
    return *p;   // L1/L2-cacheable; write-once data => stale == wrong parity
}
__device__ __forceinline__ void rec_store(unsigned long long* p, unsigned long long v) {
    __hip_atomic_store(p, v, __ATOMIC_RELAXED, __HIP_MEMORY_SCOPE_AGENT);
}
__device__ __forceinline__ unsigned ctrl_ld(const unsigned* p) {
    return __hip_atomic_load(p, __ATOMIC_RELAXED, __HIP_MEMORY_SCOPE_AGENT);
}
__device__ __forceinline__ void ctrl_st(unsigned* p, unsigned v) {
    __hip_atomic_store(p, v, __ATOMIC_RELAXED, __HIP_MEMORY_SCOPE_AGENT);
}
__device__ __forceinline__ bool unwritten(unsigned long long v, unsigned runpar) {
    return ((unsigned)v >> 31) != runpar;   // lo sign bit = run parity tag
}
__device__ __forceinline__ unsigned long long poll_written(
        const unsigned long long* src, unsigned long long v, unsigned runpar) {
    int guard = 0;
    while (unwritten(v, runpar)) {
        if (guard >= 2) __builtin_amdgcn_s_sleep(1);   // fast-retry first
        v = rec_load(src);                             // authoritative (agent)
        if (++guard > (1 << 18)) break;                // fail loud, not hung
    }
    return v;
}

// Raw barrier: drain LDS only (NOT vmcnt) -- prefetch loads / publish store
// stay in flight across the barrier. Compiler still inserts counted vmcnt
// waits before any use of load results.
#define BAR_LDS() do {                                      \
    asm volatile("s_waitcnt lgkmcnt(0)" ::: "memory");      \
    __builtin_amdgcn_s_barrier();                           \
    asm volatile("" ::: "memory");                          \
} while (0)

__global__ __launch_bounds__(TPB, 4)
void snn_main(const float* __restrict__ inputs,
              const float* __restrict__ w,
              const float* __restrict__ w_in,
              const float* __restrict__ w_out,
              const float* __restrict__ dmap,
              const int*   __restrict__ delays,
              const float* __restrict__ w_signs,
              const float* __restrict__ p,
              const float* __restrict__ A_p,
              const float* __restrict__ A_d,
              unsigned long long* __restrict__ rec,
              float* __restrict__ h2buf,
              unsigned* __restrict__ ctrl,
              float* __restrict__ out)
{
    // LDS: sxq[d][e] padded planes = {syn_p, xbar|spikebit}. 16512 B, single buf.
    __shared__ float2 sxq[DD*EPAD];
    __shared__ float  inp_s[T*OPB];        // per-block input-current slice
    __shared__ float  red[16*OPB];         // 16 wave partials for the e-reduction
    __shared__ unsigned int spikebits_s[T];// this block's 16 neurons' spikes per step
    __shared__ float  wout16_s[OPB*NO];    // w_out rows of this block's neurons
    __shared__ float  h2_s[T*NO];          // last-block scan staging
    __shared__ int    last_s;

    const int tid     = threadIdx.x;
    const int bid     = blockIdx.x;
    const int b       = bid & 7;
    const int chunk   = bid >> 3;
    const int o_base  = chunk * OPB;
    const int o_local = tid & 15;
    const int e_grp   = tid >> 4;          // 0..63
    const int o       = o_base + o_local;
    const int slotid  = tid & 511;         // rec slot this thread stages
    const int hi      = tid >> 9;          // plane-pair selector (wave-uniform)

    // ---------------- init (runs every launch: ws is re-poisoned) -----------
    unsigned runpar;
    if (ctrl_ld(ctrl + C_HDR) != MAGIC) {
        // fill own rec slice: lo-sign=1 => "unwritten for run parity 0"
        rec_store(rec + (size_t)bid * (REC_ELEMS / NBLK) + tid,
                  0x0000000080000000ull);
        // zero own h2 slice
        if (tid < (B*T*NO) / NBLK)
            ctrl_st((unsigned*)h2buf + (size_t)bid * ((B*T*NO) / NBLK) + tid, 0u);
        if (bid == 0 && tid < 10) ctrl_st(ctrl + tid, 0u);  // cnt[8], gcnt, par
        __syncthreads();                    // drains vmcnt(0): all stores acked
        if (tid == 0) ctrl_st(ctrl + C_DONE + bid, MAGIC);
        // single grid arrival barrier: thread j (<256) watches done[j]
        if (tid < NBLK) {
            int guard = 0;
            while (ctrl_ld(ctrl + C_DONE + tid) != MAGIC) {
                __builtin_amdgcn_s_sleep(2);
                if (++guard > (1 << 20)) break;
            }
        }
        __syncthreads();
        runpar = 0u;
    } else {
        runpar = ctrl_ld(ctrl + C_PAR);     // ws persisted: fast path
    }

    // ---- publish slot 0 (zero record, parity-tagged) FIRST ----
    if (tid < OPB) {
        rec_store(rec + (size_t)(0*B + b)*NN + o_base + tid,
                  (unsigned long long)(runpar << 31));
    }
    if (tid == 0) spikebits_s[0] = 0u;

    // ---------------- per-lane synapse constants (registers) -----------------
    float wv[SPL], ap[SPL], ad[SPL], ws[SPL];
    int   laddr[SPL];                 // precomputed LDS byte offset of (d,e) slot
    #pragma unroll
    for (int i = 0; i < SPL; ++i) {
        const int e = e_grp + EGR*i;
        wv[i] = w_signs[e] * fabsf(w[e*NN + o]);
        ap[i] = A_p[e*NN + o];
        ad[i] = A_d[e*NN + o];
        int d = 0;                    // argmax_d of one-hot dmap
        if (dmap[1*NN*NN + e*NN + o] != 0.0f) d = 1;
        if (dmap[2*NN*NN + e*NN + o] != 0.0f) d = 2;
        if (dmap[3*NN*NN + e*NN + o] != 0.0f) d = 3;
        ws[i]    = 1.0f;
        laddr[i] = (d*EPAD + e) * 8;
    }
    int del[DD];
    #pragma unroll
    for (int d = 0; d < DD; ++d) del[d] = delays[d];
    // plane ownership: hi=0 -> {1,3}, hi=1 -> {2,0}; delay-1 plane (d=0) LAST
    const int dj0 = hi ? 2 : 1;
    const int dj1 = hi ? 0 : 3;

    // ---------------- prologue: inp[b,t,o] slice = inputs @ w_in -------------
    {
        float* win = (float*)sxq;     // 4096 floats alias sxq, prologue-only
        #pragma unroll
        for (int q = 0; q < NI*OPB/TPB; ++q) {
            const int k = q*TPB + tid;
            const int c = k >> 4, oo = k & 15;
            win[c*OPB + oo] = w_in[c*NN + o_base + oo];
        }
        __syncthreads();
        {   // one (t,o) entry per thread: 256-MAC row
            const int tj = tid >> 4;
            const float* inrow = inputs + (size_t)(b*T + tj)*NI;
            float a = 0.f;
            for (int c = 0; c < NI; ++c) a += inrow[c] * win[c*OPB + o_local];
            __syncthreads();          // all win reads done before overwrite below
            inp_s[tj*OPB + o_local] = a;
        }
    }

    // zero-fill sxq for step 0 (all delays > 0 => all gathered slots are zero)
    if (tid < 512) {
        #pragma unroll
        for (int d = 0; d < DD; ++d)
            sxq[d*EPAD + tid] = make_float2(0.f, 0.f);
    }
    __syncthreads();

    // neuron state, replicated across the 64 e_grp threads sharing an o
    float mem = 0.f, w_p = 0.f, x_bar = 0.f, u_pot = 0.f, u_dep = 0.f;
    const float p_o  = p[o];
    const float pd_o = (p_o < 0.f) ? 1.f : 0.f;

    for (int t = 0; t < T; ++t) {
        // ---- prefetch this thread's 2 delay planes for step t+1 ----
        unsigned long long pf0 = 0ull, pf1 = 0ull;
        if (t + 1 < T) {
            if (t + 1 >= del[dj0]) {   // dj0 is always a delay>=2 plane
                const int s = (t + 1 - del[dj0]) & 63;
                pf0 = rec_load_plain(rec + (size_t)(s*B + b)*NN + slotid);
            }
            if (t + 1 >= del[dj1]) {   // dj1: delay-1 (hi=1, agent) or delay-5 (plain)
                const int s = (t + 1 - del[dj1]) & 63;
                const unsigned long long* src = rec + (size_t)(s*B + b)*NN + slotid;
                pf1 = (del[dj1] == 1) ? rec_load(src) : rec_load_plain(src);
            }
        }

        // ---- acc-only loop: 8 synapses/lane, staged v[] kept in registers ----
        const float spike = (mem > 1.0f) ? 1.0f : 0.0f;
        const float pg  = spike * fmaxf(u_pot, 0.f);   // STDP gates: pre-update u's
        const float udr = fmaxf(u_dep, 0.f);
        float2 v[SPL];
        float acc = 0.f;
        #pragma unroll
        for (int i = 0; i < SPL; ++i) {
            v[i] = *(const float2*)((const char*)sxq + laddr[i]);
            acc = fmaf(v[i].x, wv[i]*ws[i], acc);      // syn uses OLD w_stdp
        }
        // reduce over e: intra-wave xor-shuffles (4 e_grps/wave), 16 wave partials
        float a2 = acc + __shfl_xor(acc, 16);
        a2 += __shfl_xor(a2, 32);
        if ((tid & 63) < 16) red[(tid >> 6)*16 + o_local] = a2;
        BAR_LDS();         // B1: red visible block-wide; vmem stays in flight
        float syn = 0.f;
        #pragma unroll
        for (int k = 0; k < 16; ++k) syn += red[k*16 + o_local];

        // ---- state updates (reference order; u's use pre-update mem) ----
        const float wp_new = 0.85f*w_p + spike * p_o * (1.f + pd_o*w_p);
        const float xb_new = 0.95f*x_bar + 0.05f*spike;
        u_pot = 0.95f*u_pot + 0.05f*mem;
        u_dep = 0.95f*u_dep + 0.05f*mem;
        mem   = 0.9f*mem + inp_s[t*OPB + o_local] + syn - spike;
        w_p   = wp_new;
        x_bar = xb_new;

        // ---- publish record for step t+1 EARLY (before STDP + staging) ----
        if (t + 1 < T && tid < OPB) {
            const float spike1 = (mem > 1.0f) ? 1.0f : 0.0f;
            const float sp = spike1 * (1.f + w_p);     // >= 0: sign bit free
            const unsigned int xu = __float_as_uint(x_bar) | (spike1 != 0.f ? 0x80000000u : 0u);
            const unsigned int lo = __float_as_uint(sp) | (runpar << 31);
            const unsigned long long pk = ((unsigned long long)xu << 32) | lo;
            rec_store(rec + (size_t)((t+1)*B + b)*NN + o_base + tid, pk);
            const unsigned long long bal = __ballot(spike1 != 0.0f);
            if (tid == 0) spikebits_s[t+1] = (unsigned int)bal;
        }

        // ---- STDP ws-update (covers publish visibility; pre-update gates) ----
        #pragma unroll
        for (int i = 0; i < SPL; ++i) {
            const unsigned int xu = __float_as_uint(v[i].y);
            const float dep = ((int)xu < 0) ? ad[i]*udr : 0.f;  // X in sign bit
            const float pot = (ap[i]*pg) * fabsf(v[i].y);
            ws[i] = fminf(fmaxf(ws[i] + pot - dep, 0.f), 2.f);
        }

        // ---- stage step t+1 into sxq from prefetch; delay-1 plane LAST ----
        if (t + 1 < T) {
            {
                unsigned long long v0 = (unsigned long long)(runpar << 31);
                if (t + 1 >= del[dj0]) {
                    const int s = (t + 1 - del[dj0]) & 63;
                    v0 = poll_written(rec + (size_t)(s*B + b)*NN + slotid, pf0, runpar);
                }
                sxq[dj0*EPAD + slotid] =
                    make_float2(__uint_as_float((unsigned)v0 & 0x7fffffffu),
                                __uint_as_float((unsigned)(v0 >> 32)));
            }
            {
                unsigned long long v1 = (unsigned long long)(runpar << 31);
                if (t + 1 >= del[dj1]) {
                    const int s = (t + 1 - del[dj1]) & 63;
                    v1 = poll_written(rec + (size_t)(s*B + b)*NN + slotid, pf1, runpar);
                }
                sxq[dj1*EPAD + slotid] =
                    make_float2(__uint_as_float((unsigned)v1 & 0x7fffffffu),
                                __uint_as_float((unsigned)(v1 >> 32)));
            }
        }
        BAR_LDS();         // B2: sxq staged for t+1; red reads of t done
    }

    // ================= fused readout =================
    // (1) per-block partial h2 over its own 16 neurons, from the LDS spike bitmap
    if (tid < OPB*NO) wout16_s[tid] = w_out[(o_base + (tid >> 5))*NO + (tid & 31)];
    __syncthreads();

    const int g  = tid >> 5;        // 0..31
    const int oo = tid & 31;        // output index
    #pragma unroll
    for (int j = 0; j < 2; ++j) {
        const int t = g*2 + j;
        const unsigned int bits = spikebits_s[t];
        float a = 0.f;
        #pragma unroll
        for (int i = 0; i < OPB; ++i)
            if (bits & (1u << i)) a += wout16_s[i*NO + oo];
        if (a != 0.f) atomicAdd(h2buf + ((size_t)b*T + t)*NO + oo, a);
    }
    __threadfence();                 // make our h2 atomics visible before arrival
    __syncthreads();
    if (tid == 0) last_s = (atomicAdd(ctrl + C_CNT + b, 1u) == 31u) ? 1 : 0;
    __syncthreads();

    if (last_s) {
        // (2) last-arriving block of batch b: gather h2, leaky scan, reset h2
        __threadfence();
        #pragma unroll
        for (int j = 0; j < 2; ++j) {
            const int t = g*2 + j;
            h2_s[t*NO + oo] = __hip_atomic_load(h2buf + ((size_t)b*T + t)*NO + oo,
                                                __ATOMIC_RELAXED, __HIP_MEMORY_SCOPE_AGENT);
        }
        __syncthreads();
        #pragma unroll
        for (int j = 0; j < 2; ++j) {   // zero-after-read (persisted-ws path safety)
            const int t = g*2 + j;
            __hip_atomic_store((unsigned*)(h2buf + ((size_t)b*T + t)*NO + oo), 0u,
                               __ATOMIC_RELAXED, __HIP_MEMORY_SCOPE_AGENT);
        }
        if (tid < NO) {
            float st = 0.f;
            for (int t = 0; t < T; ++t) {
                st = 0.9f*st + h2_s[t*NO + tid];
                out[((size_t)b*T + t)*NO + tid] = st;
            }
        }
    }

    // ---- global arrival: the 256th block flips run state for the next launch ----
    if (tid == 0) {
        const unsigned gar = __hip_atomic_fetch_add(ctrl + C_GCNT, 1u,
                                                    __ATOMIC_ACQ_REL, __HIP_MEMORY_SCOPE_AGENT);
        if (gar == NBLK - 1) {
            for (int i = 0; i < 8; ++i) ctrl_st(ctrl + C_CNT + i, 0u);
            ctrl_st(ctrl + C_GCNT, 0u);
            ctrl_st(ctrl + C_PAR, runpar ^ 1u);
            ctrl_st(ctrl + C_HDR, MAGIC);
        }
    }
}

extern "C" void kernel_launch(void* const* d_in, const int* in_sizes, int n_in,
                              void* d_out, int out_size, void* d_ws, size_t ws_size,
                              hipStream_t stream)
{
    const float* inputs  = (const float*)d_in[0];
    const float* w       = (const float*)d_in[1];
    const float* w_in    = (const float*)d_in[2];
    const float* w_out   = (const float*)d_in[3];
    const float* dmap    = (const float*)d_in[4];
    const int*   delays  = (const int*)  d_in[5];
    const float* w_signs = (const float*)d_in[6];
    const float* p       = (const float*)d_in[7];
    const float* A_p     = (const float*)d_in[8];
    const float* A_d     = (const float*)d_in[9];

    char* wsb = (char*)d_ws;
    unsigned long long* rec = (unsigned long long*)wsb;            // 2 MB packed records
    float* h2buf = (float*)(wsb + (size_t)REC_ELEMS*8);            // 64 KB
    unsigned* ctrl = (unsigned*)(wsb + (size_t)REC_ELEMS*8 + (size_t)B*T*NO*4);

    // Single dispatch: init (parity fill + one grid tag-barrier) runs in-kernel.
    hipLaunchKernelGGL(snn_main, dim3(NBLK), dim3(TPB), 0, stream,
                       inputs, w, w_in, w_out, dmap, delays, w_signs, p, A_p, A_d,
                       rec, h2buf, ctrl, (float*)d_out);
}